// Round 10
// baseline (59.705 us; speedup 1.0000x reference)
//
#include <hip/hip_runtime.h>

// patches: [N=128, C=4, P=32, P, P] fp32 ; vol/out: [B=2, C=4, 128,128,128] fp32
// centers: [N,3] int32 ; lo = center-16 ; patch n -> batch b = n/64
// out = 0.5*vol + 0.5*scatter(patches), computed as a GATHER (no atomics).
// R10: CHANNEL-SPLIT decomposition. One thread = one channel x 4 d-voxels.
//  - 16384 blocks x 256 threads (4x R5's wave count) -> TLP hides VMEM latency
//  - tiny per-thread state (1 vol4 + 1 acc4 + 2 gather float4s) -> low VGPR,
//    high occupancy (R9 post-mortem: VGPR 52 halved occupancy, regressed)
//  - aligned ka/kb float4 gather + wave-uniform shift (k0&3 lane-invariant)
//  - per-block ballot-compacted candidate list (recomputed per channel block)

constexpr int C = 4, H = 128, P = 32;
constexpr int NPB  = 64;               // patches per batch
constexpr int PCH4 = P * P * P / 4;    // patch channel stride in float4 (8192)

__global__ __launch_bounds__(256) void patch_gather_kernel(
        const float4* __restrict__ patches4,
        const int*   __restrict__ centers,
        const float4* __restrict__ vol4,
        float4* __restrict__ out4) {
    __shared__ int s_list[NPB];
    __shared__ int s_n;

    int blk = blockIdx.x;              // (((b*4 + c)*128 + h)*16 + wgrp)
    int wgrp = blk & 15;
    int h    = (blk >> 4) & 127;
    int c    = (blk >> 11) & 3;
    int b    = blk >> 13;
    int tid  = threadIdx.x;

    int w0 = wgrp << 3;                // block covers w0..w0+7
    int d4 = tid & 31;
    int w  = w0 + (tid >> 5);
    int d0 = d4 << 2;

    // ---- issue vol load EARLY (independent of everything below) --------
    int base4 = (((b * C + c) * H + h) * H + w) * 32 + d4;
    float4 v = vol4[base4];

    // ---- wave0: ballot-compacted per-block candidate list --------------
    if (tid < 64) {
        int lo0 = centers[(b * NPB + tid) * 3 + 0] - 16;
        int lo1 = centers[(b * NPB + tid) * 3 + 1] - 16;
        int lo2 = centers[(b * NPB + tid) * 3 + 2] - 16;
        bool hit = ((unsigned)(h - lo0) < 32u) &&
                   ((unsigned)(w0 - lo1 + 7) < 39u);   // w-range intersect
        unsigned long long m = __ballot(hit);
        if (hit) {
            int pos = __popcll(m & ((1ull << tid) - 1ull));
            s_list[pos] = (tid << 21) | ((h - lo0) << 14) | (lo1 << 7) | lo2;
        }
        if (tid == 0) s_n = __popcll(m);
    }
    __syncthreads();

    int nh = s_n;
    float4 acc = make_float4(0.f, 0.f, 0.f, 0.f);
    const float4* pbat = patches4 + ((size_t)b * NPB * C + c) * PCH4;

    for (int i = 0; i < nh; ++i) {
        int e   = s_list[i];           // broadcast LDS read
        int pn  = e >> 21;
        int hi  = (e >> 14) & 31;
        int lo1 = (e >> 7) & 127;
        int lo2 = e & 127;
        int wi  = w - lo1;
        int k0  = d0 - lo2;            // patch-k of this thread's first elem
        bool hit = ((unsigned)wi < 32u) && (k0 > -4) && (k0 < 32);

        float4 z = make_float4(0.f, 0.f, 0.f, 0.f);
        float4 A = z, Bv = z;
        if (hit) {
            int q = (k0 + 4) >> 2;     // 0..8
            int ka = q - 1, kb = q;    // aligned float4 window
            const float4* pr = pbat + (size_t)pn * C * PCH4 + (hi * 32 + wi) * 8;
            if ((unsigned)ka < 8u) A  = pr[ka];
            if ((unsigned)kb < 8u) Bv = pr[kb];
        }
        // k0 & 3 == (-lo2) & 3 : identical for every lane (d0 % 4 == 0)
        int shift = __builtin_amdgcn_readfirstlane(k0 & 3);
        switch (shift) {
        case 0:
            acc.x += A.x; acc.y += A.y; acc.z += A.z; acc.w += A.w; break;
        case 1:
            acc.x += A.y; acc.y += A.z; acc.z += A.w; acc.w += Bv.x; break;
        case 2:
            acc.x += A.z; acc.y += A.w; acc.z += Bv.x; acc.w += Bv.y; break;
        default:
            acc.x += A.w; acc.y += Bv.x; acc.z += Bv.y; acc.w += Bv.z; break;
        }
    }

    // ---- epilogue: out = 0.5*(vol + acc) -------------------------------
    float4 o;
    o.x = (v.x + acc.x) * 0.5f;
    o.y = (v.y + acc.y) * 0.5f;
    o.z = (v.z + acc.z) * 0.5f;
    o.w = (v.w + acc.w) * 0.5f;
    out4[base4] = o;
}

extern "C" void kernel_launch(void* const* d_in, const int* in_sizes, int n_in,
                              void* d_out, int out_size, void* d_ws, size_t ws_size,
                              hipStream_t stream) {
    const float* patches = (const float*)d_in[0];
    const float* vol     = (const float*)d_in[1];
    const int*   centers = (const int*)d_in[2];
    float* out = (float*)d_out;

    patch_gather_kernel<<<16384, 256, 0, stream>>>(
        (const float4*)patches, centers, (const float4*)vol, (float4*)out);
}

// Round 12
// 57.194 us; speedup vs baseline: 1.0439x; 1.0439x over previous
//
#include <hip/hip_runtime.h>

// patches: [N=128, C=4, P=32, P, P] fp32 ; vol/out: [B=2, C=4, 128,128,128] fp32
// centers: [N,3] int32 ; lo = center-16 (lo in [0,96]) ; patch n -> batch b = n/64
// out = 0.5*vol + 0.5*scatter(patches), computed as a GATHER (no atomics).
// R11: BARRIER-FREE wave-autonomous filter.
//  - 64 patches == 64 lanes: each wave ballots its own candidate set and
//    walks the mask with __ffsll + __shfl descriptor broadcast.
//    No __syncthreads, no LDS, no wave0 specialization (R10 post-mortem:
//    occupancy is ample; the serialized prologue/barrier was the suspect).
//  - channel-split mapping (R10): 1 thread = 1 channel x 4 d-voxels, VGPR ~20
//  - aligned ka/kb float4 gather + wave-uniform shift (k0&3 lane-invariant)

constexpr int C = 4, H = 128, P = 32;
constexpr int NPB  = 64;               // patches per batch
constexpr int PCH4 = P * P * P / 4;    // patch channel stride in float4 (8192)

__global__ __launch_bounds__(256) void patch_gather_kernel(
        const float4* __restrict__ patches4,
        const int*   __restrict__ centers,
        const float4* __restrict__ vol4,
        float4* __restrict__ out4) {
    int blk = blockIdx.x;              // (((b*4 + c)*128 + h)*16 + wgrp)
    int wgrp = blk & 15;
    int h    = (blk >> 4) & 127;
    int c    = (blk >> 11) & 3;
    int b    = blk >> 13;
    int tid  = threadIdx.x;

    int w0 = wgrp << 3;                // block covers w0..w0+7
    int d4 = tid & 31;
    int w  = w0 + (tid >> 5);
    int d0 = d4 << 2;

    // ---- issue vol load EARLY ------------------------------------------
    int base4 = (((b * C + c) * H + h) * H + w) * 32 + d4;
    float4 v = vol4[base4];

    // ---- wave-autonomous filter: lane l evaluates patch l --------------
    int lane = tid & 63;
    int cb   = (b * NPB + lane) * 3;
    int lo0  = centers[cb + 0] - 16;   // in [0,96]
    int lo1  = centers[cb + 1] - 16;
    int lo2  = centers[cb + 2] - 16;
    bool cand = ((unsigned)(h - lo0) < 32u) &&
                ((unsigned)(w0 - lo1 + 7) < 39u);      // w-range intersect
    int packed = ((h - lo0) << 14) | (lo1 << 7) | lo2; // hi | lo1 | lo2
    unsigned long long mask = __ballot(cand);

    float4 acc = make_float4(0.f, 0.f, 0.f, 0.f);
    const float4* pbat = patches4 + ((size_t)b * NPB * C + c) * PCH4;

    while (mask) {
        int l = __ffsll((long long)mask) - 1;          // candidate patch = lane l
        mask &= mask - 1;
        int e = __shfl(packed, l);                     // broadcast descriptor
        int hi   = (e >> 14) & 31;
        int plo1 = (e >> 7) & 127;
        int plo2 = e & 127;
        int wi = w - plo1;
        int k0 = d0 - plo2;            // patch-k of this thread's first elem
        bool hit = ((unsigned)wi < 32u) && (k0 > -4) && (k0 < 32);

        float4 z = make_float4(0.f, 0.f, 0.f, 0.f);
        float4 A = z, Bv = z;
        if (hit) {
            int q = (k0 + 4) >> 2;     // 0..8
            int ka = q - 1, kb = q;    // aligned float4 window
            const float4* pr = pbat + (size_t)l * C * PCH4 + (hi * 32 + wi) * 8;
            if ((unsigned)ka < 8u) A  = pr[ka];
            if ((unsigned)kb < 8u) Bv = pr[kb];
        }
        // k0 & 3 == (-plo2) & 3 : identical for every lane (d0 % 4 == 0)
        int shift = __builtin_amdgcn_readfirstlane(k0 & 3);
        switch (shift) {
        case 0:
            acc.x += A.x; acc.y += A.y; acc.z += A.z; acc.w += A.w; break;
        case 1:
            acc.x += A.y; acc.y += A.z; acc.z += A.w; acc.w += Bv.x; break;
        case 2:
            acc.x += A.z; acc.y += A.w; acc.z += Bv.x; acc.w += Bv.y; break;
        default:
            acc.x += A.w; acc.y += Bv.x; acc.z += Bv.y; acc.w += Bv.z; break;
        }
    }

    // ---- epilogue: out = 0.5*(vol + acc) -------------------------------
    float4 o;
    o.x = (v.x + acc.x) * 0.5f;
    o.y = (v.y + acc.y) * 0.5f;
    o.z = (v.z + acc.z) * 0.5f;
    o.w = (v.w + acc.w) * 0.5f;
    out4[base4] = o;
}

extern "C" void kernel_launch(void* const* d_in, const int* in_sizes, int n_in,
                              void* d_out, int out_size, void* d_ws, size_t ws_size,
                              hipStream_t stream) {
    const float* patches = (const float*)d_in[0];
    const float* vol     = (const float*)d_in[1];
    const int*   centers = (const int*)d_in[2];
    float* out = (float*)d_out;

    patch_gather_kernel<<<16384, 256, 0, stream>>>(
        (const float4*)patches, centers, (const float4*)vol, (float4*)out);
}